// Round 10
// baseline (169.290 us; speedup 1.0000x reference)
//
#include <hip/hip_runtime.h>

// N=8, L=2048, E=1024, V=512. Only l=L-1 feeds logits.
// R10: TWO kernels.
//  K1 role-split: blocks 0..511 pack tokens->bits (the only 64 MB pass);
//                 blocks 512..767 compute q_row (Wa_w read exactly once).
//  K2: flash-from-bits per (n,chunk); no-max softmax (p=exp(s), |s|<~40 safe);
//      writes unnormalized pa + z_c; fan-in: last block per n (atomic counter)
//      combines all 64 chunks in FIXED order and does the out-GEMV inline.
#define NB 8
#define LS 2048
#define ED 1024
#define VD 512
#define CM 32           // m-rows per flash block
#define CH (LS / CM)    // 64 chunks
typedef unsigned long long u64;

__device__ inline float wave_reduce_sum(float v) {
    #pragma unroll
    for (int off = 32; off > 0; off >>= 1)
        v += __shfl_down(v, off, 64);
    return v;
}

// K1: blocks 0..511 = pack role (wave packs 8 rows).
//     bit map: e = k + 4*lane + j -> word ((e>>8)<<2)|(e&3), bit (e>>2)&63.
//     blocks 512..767 = qrow role: q_row[n,f] = Wa_b[f] + xs[n] . Wa_w[f].
__global__ __launch_bounds__(256) void k_pack_qrow(const int* __restrict__ tokens,
                                                   const float* __restrict__ Wa_w,
                                                   const float* __restrict__ Wa_b,
                                                   float* __restrict__ q_row,
                                                   u64* __restrict__ pk_g) {
    __shared__ int xs[NB][ED];          // 32 KB (qrow role only)
    int b = blockIdx.x, t = threadIdx.x;
    int wave = t >> 6, lane = t & 63;
    if (b < 512) {
        #pragma unroll
        for (int i = 0; i < 8; ++i) {
            int row = b * 32 + wave * 8 + i;        // row = n*LS + m, 0..16383
            const int* xr = tokens + (size_t)row * ED;
            u64* pkr = pk_g + (size_t)row * 16;
            #pragma unroll
            for (int k = 0; k < ED; k += 256) {
                int idx = k + lane * 4;
                int4 tv = *reinterpret_cast<const int4*>(xr + idx);
                u64 b0 = __ballot(tv.x != 0);
                u64 b1 = __ballot(tv.y != 0);
                u64 b2 = __ballot(tv.z != 0);
                u64 b3 = __ballot(tv.w != 0);
                u64 bb = b0;
                bb = (lane == 1) ? b1 : bb;
                bb = (lane == 2) ? b2 : bb;
                bb = (lane == 3) ? b3 : bb;
                if (lane < 4) pkr[((k >> 8) << 2) + lane] = bb;
            }
        }
    } else {
        #pragma unroll
        for (int i = 0; i < 8; ++i) {
            int v4 = i * 256 + t;
            int n  = v4 >> 8;
            int e  = (v4 & 255) * 4;
            *reinterpret_cast<int4*>(&xs[n][e]) =
                *reinterpret_cast<const int4*>(&tokens[((size_t)n * LS + (LS - 1)) * ED + e]);
        }
        __syncthreads();
        int f = (b - 512) * 4 + wave;
        const float* wrow = Wa_w + (size_t)f * ED;
        float acc[NB] = {0.f, 0.f, 0.f, 0.f, 0.f, 0.f, 0.f, 0.f};
        #pragma unroll
        for (int k = 0; k < ED; k += 256) {
            int idx = k + lane * 4;
            float4 w = *reinterpret_cast<const float4*>(wrow + idx);
            #pragma unroll
            for (int n = 0; n < NB; ++n) {
                int4 tv = *reinterpret_cast<const int4*>(&xs[n][idx]);
                acc[n] += (float)tv.x * w.x + (float)tv.y * w.y
                        + (float)tv.z * w.z + (float)tv.w * w.w;
            }
        }
        #pragma unroll
        for (int n = 0; n < NB; ++n) {
            float s = wave_reduce_sum(acc[n]);
            if (lane == 0) q_row[n * ED + f] = s + Wa_b[f];
        }
    }
}

// K2: flash + fan-in output. Block (512 thr) per (n, chunk of 32 m).
__global__ __launch_bounds__(512) void k_flash_out(const float* __restrict__ q_row,
                                                   const u64* __restrict__ pk_g,
                                                   const float* __restrict__ Wb_w,
                                                   const float* __restrict__ Wb_b,
                                                   float* __restrict__ pa,
                                                   float* __restrict__ z_g,
                                                   unsigned* __restrict__ done,
                                                   float* __restrict__ out) {
    int n = blockIdx.x >> 6;      // /CH
    int c = blockIdx.x & (CH - 1);
    int t = threadIdx.x;
    int wave = t >> 6, lane = t & 63;

    __shared__ u64   pk[CM * 16];   // 4 KB
    __shared__ float q_perm[ED];    // 4 KB
    __shared__ float p_lds[CM];
    __shared__ float a_lds[ED];     // 4 KB (fan-in only)
    __shared__ int   last_s;

    pk[t] = pk_g[((size_t)(n * LS + c * CM)) * 16 + t];
    {
        float2 qq = *reinterpret_cast<const float2*>(&q_row[n * ED + t * 2]);
        int e0 = t * 2, e1 = e0 + 1;
        q_perm[((((e0 >> 8) << 2) | (e0 & 3)) << 6) | ((e0 >> 2) & 63)] = qq.x;
        q_perm[((((e1 >> 8) << 2) | (e1 & 3)) << 6) | ((e1 >> 2) & 63)] = qq.y;
    }
    __syncthreads();

    // ---- phase 1: masked-add scores -> p = exp(s) (no max-sub) ----
    #pragma unroll
    for (int i = 0; i < 4; ++i) {
        int m = wave + 8 * i;
        float acc = 0.f;
        #pragma unroll
        for (int w = 0; w < 16; ++w) {
            u64   word = pk[m * 16 + w];            // broadcast read
            float qv   = q_perm[(w << 6) | lane];   // conflict-free
            acc += ((word >> lane) & 1ull) ? qv : 0.f;
        }
        acc = wave_reduce_sum(acc);
        if (lane == 0) p_lds[m] = expf(acc);
    }
    __syncthreads();

    // ---- phase 2: z_c = sum_m p_m (wave 0) ----
    if (wave == 0) {
        float p = (lane < CM) ? p_lds[lane] : 0.f;
        float z = p;
        #pragma unroll
        for (int off = 32; off > 0; off >>= 1) z += __shfl_xor(z, off, 64);
        if (lane == 0) z_g[blockIdx.x] = z;
    }

    // ---- phase 3: unnormalized weighted bit-sum; e0 = t, e1 = t + 512 ----
    int w0  = ((t >> 8) << 2) | (t & 3);
    int bit = (t >> 2) & 63;
    float a0 = 0.f, a1 = 0.f;
    #pragma unroll 8
    for (int m = 0; m < CM; ++m) {
        float p  = p_lds[m];
        u64   lo = pk[m * 16 + w0];
        u64   hi = pk[m * 16 + w0 + 8];
        a0 += ((lo >> bit) & 1ull) ? p : 0.f;
        a1 += ((hi >> bit) & 1ull) ? p : 0.f;
    }
    float* par = pa + (size_t)blockIdx.x * ED;
    par[t]       = a0;
    par[t + 512] = a1;

    // ---- fan-in: last block per n does combine + GEMV ----
    __threadfence();              // release my pa/z writes
    __syncthreads();              // all threads' fences done
    if (t == 0) last_s = (atomicAdd(&done[n], 1u) == CH - 1) ? 1 : 0;
    __syncthreads();
    if (!last_s) return;
    __threadfence();              // acquire: others' pa/z now visible

    float Z = 0.f;
    #pragma unroll 8
    for (int cc = 0; cc < CH; ++cc) Z += z_g[n * CH + cc];   // fixed order
    float invZ = 1.f / Z;

    float s0 = 0.f, s1 = 0.f;
    #pragma unroll 4
    for (int cc = 0; cc < CH; ++cc) {                        // fixed order
        const float* pr = pa + ((size_t)(n * CH + cc)) * ED;
        s0 += pr[t];
        s1 += pr[t + 512];
    }
    a_lds[t]       = s0 * invZ;
    a_lds[t + 512] = s1 * invZ;
    __syncthreads();

    // GEMV: 8 waves x 64 v each
    for (int j = 0; j < 64; ++j) {
        int v = wave * 64 + j;
        const float* wr = Wb_w + (size_t)v * ED;
        float d = 0.f;
        #pragma unroll
        for (int k = 0; k < ED; k += 256) {
            int idx = k + lane * 4;
            float4 wv = *reinterpret_cast<const float4*>(wr + idx);
            float4 av = *reinterpret_cast<const float4*>(&a_lds[idx]);
            d += av.x * wv.x + av.y * wv.y + av.z * wv.z + av.w * wv.w;
        }
        d = wave_reduce_sum(d);
        if (lane == 0) out[n * VD + v] = d + Wb_b[v];
    }
}

extern "C" void kernel_launch(void* const* d_in, const int* in_sizes, int n_in,
                              void* d_out, int out_size, void* d_ws, size_t ws_size,
                              hipStream_t stream) {
    const int*   tokens = (const int*)  d_in[0];
    const float* Wa_w   = (const float*)d_in[1];
    const float* Wa_b   = (const float*)d_in[2];
    const float* Wb_w   = (const float*)d_in[3];
    const float* Wb_b   = (const float*)d_in[4];
    float* out = (float*)d_out;

    unsigned* done = (unsigned*)d_ws;                        // 8 counters (256 B pad)
    u64*   pk_g  = (u64*)((char*)d_ws + 256);                // 8*2048*16 u64 = 2 MB
    float* q_row = (float*)(pk_g + (size_t)NB * LS * 16);    // 8192
    float* pa    = q_row + NB * ED;                          // 8*64*1024 = 524288
    float* z_g   = pa + (size_t)NB * CH * ED;                // 512

    hipMemsetAsync(d_ws, 0, 256, stream);                    // zero fan-in counters
    // 1) pack (0..511) + qrow (512..767): the only 64 MB pass
    k_pack_qrow<<<dim3(768), dim3(256), 0, stream>>>(tokens, Wa_w, Wa_b, q_row, pk_g);
    // 2) flash from bits + fan-in combine/GEMV: 512 blocks of 512
    k_flash_out<<<dim3(NB * CH), dim3(512), 0, stream>>>(q_row, pk_g, Wb_w, Wb_b,
                                                         pa, z_g, done, out);
}